// Round 1
// baseline (4317.911 us; speedup 1.0000x reference)
//
#include <hip/hip_runtime.h>

#define NN 50000
#define NE 1600000

__global__ __launch_bounds__(256) void deg_kernel(const int* __restrict__ dst,
        const float* __restrict__ ew, float* __restrict__ deg) {
    int e = blockIdx.x * 256 + threadIdx.x;
    if (e < NE) atomicAdd(&deg[dst[e]], ew[e]);
}

__global__ __launch_bounds__(256) void dinv_kernel(float* __restrict__ deg) {
    int i = blockIdx.x * 256 + threadIdx.x;
    if (i < NN) deg[i] = rsqrtf(deg[i] + 1.0f);   // +1 = self loop; always > 0
}

__global__ __launch_bounds__(256) void coef_kernel(const int* __restrict__ src,
        const int* __restrict__ dst, const float* __restrict__ ew,
        const float* __restrict__ dinv, float* __restrict__ coef) {
    int e = blockIdx.x * 256 + threadIdx.x;
    if (e < NE) coef[e] = dinv[src[e]] * ew[e] * dinv[dst[e]];
}

// C[M,N] = A[M,K]*B[K,N], row-major. Requires N%64==0, K%16==0, K%4==0.
__global__ __launch_bounds__(256) void gemm_kernel(const float* __restrict__ A,
        const float* __restrict__ B, float* __restrict__ C, int M, int N, int K) {
    const int BM = 64, BN = 64, BK = 16;
    __shared__ float As[BK][BM + 1];
    __shared__ float Bs[BK][BN];
    int bm = blockIdx.y * BM, bn = blockIdx.x * BN;
    int tid = threadIdx.x;
    int tx = tid & 15, ty = tid >> 4;
    float acc[4][4] = {};
    for (int k0 = 0; k0 < K; k0 += BK) {
        // A tile 64x16: one float4 per thread
        int ar = tid >> 2, ak = (tid & 3) << 2;
        float4 av = make_float4(0.f, 0.f, 0.f, 0.f);
        if (bm + ar < M) av = *(const float4*)(A + (size_t)(bm + ar) * K + k0 + ak);
        As[ak + 0][ar] = av.x; As[ak + 1][ar] = av.y;
        As[ak + 2][ar] = av.z; As[ak + 3][ar] = av.w;
        // B tile 16x64: one float4 per thread
        int bk = tid >> 4, bc = (tid & 15) << 2;
        *(float4*)(&Bs[bk][bc]) = *(const float4*)(B + (size_t)(k0 + bk) * N + bn + bc);
        __syncthreads();
        #pragma unroll
        for (int k = 0; k < BK; ++k) {
            float a[4], b[4];
            #pragma unroll
            for (int i = 0; i < 4; ++i) a[i] = As[k][ty * 4 + i];
            #pragma unroll
            for (int j = 0; j < 4; ++j) b[j] = Bs[k][tx * 4 + j];
            #pragma unroll
            for (int i = 0; i < 4; ++i)
                #pragma unroll
                for (int j = 0; j < 4; ++j)
                    acc[i][j] += a[i] * b[j];
        }
        __syncthreads();
    }
    #pragma unroll
    for (int i = 0; i < 4; ++i) {
        int r = bm + ty * 4 + i;
        if (r < M) {
            float4 v = make_float4(acc[i][0], acc[i][1], acc[i][2], acc[i][3]);
            *(float4*)(C + (size_t)r * N + bn + tx * 4) = v;
        }
    }
}

// One thread per (edge, float4-feature-group). fshift = log2(F/4).
__global__ __launch_bounds__(256) void agg_kernel(const int* __restrict__ src,
        const int* __restrict__ dst, const float* __restrict__ coef,
        const float* __restrict__ H, float* __restrict__ out, int F, int fshift) {
    int idx = blockIdx.x * 256 + threadIdx.x;
    int e = idx >> fshift;
    if (e >= NE) return;
    int f4 = (idx & ((1 << fshift) - 1)) << 2;
    int s = src[e], d = dst[e];
    float c = coef[e];
    float4 hv = *(const float4*)(H + (size_t)s * F + f4);
    float* o = out + (size_t)d * F + f4;
    atomicAdd(o + 0, hv.x * c);
    atomicAdd(o + 1, hv.y * c);
    atomicAdd(o + 2, hv.z * c);
    atomicAdd(o + 3, hv.w * c);
}

// A1 = relu(A1 + H1*dinv^2 + b1)   (N*128 elements)
__global__ __launch_bounds__(256) void epi1_kernel(float* __restrict__ A1,
        const float* __restrict__ H1, const float* __restrict__ dinv,
        const float* __restrict__ b) {
    int idx = blockIdx.x * 256 + threadIdx.x;
    int i = idx >> 7, f = idx & 127;
    if (i >= NN) return;
    float di = dinv[i];
    float v = A1[idx] + H1[idx] * di * di + b[f];
    A1[idx] = v > 0.0f ? v : 0.0f;
}

// out += H2*dinv^2 + b2   (N*64 elements)
__global__ __launch_bounds__(256) void epi2_kernel(float* __restrict__ out,
        const float* __restrict__ H2, const float* __restrict__ dinv,
        const float* __restrict__ b) {
    int idx = blockIdx.x * 256 + threadIdx.x;
    int i = idx >> 6, f = idx & 63;
    if (i >= NN) return;
    float di = dinv[i];
    out[idx] += H2[idx] * di * di + b[f];
}

extern "C" void kernel_launch(void* const* d_in, const int* in_sizes, int n_in,
                              void* d_out, int out_size, void* d_ws, size_t ws_size,
                              hipStream_t stream) {
    const float* x  = (const float*)d_in[0];
    const int*   ei = (const int*)d_in[1];     // [2, NE] int32 (JAX x64 disabled)
    const float* ew = (const float*)d_in[2];
    const float* W1 = (const float*)d_in[3];
    const float* b1 = (const float*)d_in[4];
    const float* W2 = (const float*)d_in[5];
    const float* b2 = (const float*)d_in[6];
    const int* src = ei;
    const int* dst = ei + NE;
    float* out = (float*)d_out;

    // workspace layout (floats), 16-float-aligned offsets:
    float* ws   = (float*)d_ws;
    float* deg  = ws;                     // NN (dinv in place after dinv_kernel)
    float* coef = ws + 50048;             // NE
    float* H1   = ws + 50048 + NE;        // NN*128; reused as H2 after epi1
    float* A1   = H1 + 6400000;           // NN*128
    // total = 14,450,048 floats = 57.8 MB

    hipMemsetAsync(deg, 0, NN * sizeof(float), stream);
    hipMemsetAsync(A1, 0, (size_t)NN * 128 * sizeof(float), stream);
    hipMemsetAsync(out, 0, (size_t)NN * 64 * sizeof(float), stream);

    deg_kernel<<<NE / 256, 256, 0, stream>>>(dst, ew, deg);
    dinv_kernel<<<(NN + 255) / 256, 256, 0, stream>>>(deg);
    coef_kernel<<<NE / 256, 256, 0, stream>>>(src, dst, ew, deg, coef);

    // Layer 1: H1 = x @ W1  [50000,256]x[256,128]
    gemm_kernel<<<dim3(2, (NN + 63) / 64), 256, 0, stream>>>(x, W1, H1, NN, 128, 256);
    agg_kernel<<<(NE * 32) / 256, 256, 0, stream>>>(src, dst, coef, H1, A1, 128, 5);
    epi1_kernel<<<(NN * 128) / 256, 256, 0, stream>>>(A1, H1, deg, b1);

    // Layer 2: H2 = A1 @ W2  [50000,128]x[128,64]  (H2 stored in H1's region)
    gemm_kernel<<<dim3(1, (NN + 63) / 64), 256, 0, stream>>>(A1, W2, H1, NN, 64, 128);
    agg_kernel<<<(NE * 16) / 256, 256, 0, stream>>>(src, dst, coef, H1, out, 64, 4);
    epi2_kernel<<<(NN * 64) / 256, 256, 0, stream>>>(out, H1, deg, b2);
}

// Round 2
// 656.463 us; speedup vs baseline: 6.5775x; 6.5775x over previous
//
#include <hip/hip_runtime.h>

#define NN 50000
#define NE 1600000

// deg[d] += ew[e];  cnt[d] += 1   (fused single pass over edges)
__global__ __launch_bounds__(256) void deg_count_kernel(const int* __restrict__ dst,
        const float* __restrict__ ew, float* __restrict__ deg, int* __restrict__ cnt) {
    int e = blockIdx.x * 256 + threadIdx.x;
    if (e < NE) {
        int d = dst[e];
        atomicAdd(&deg[d], ew[e]);
        atomicAdd(&cnt[d], 1);
    }
}

__global__ __launch_bounds__(256) void dinv_kernel(float* __restrict__ deg) {
    int i = blockIdx.x * 256 + threadIdx.x;
    if (i < NN) deg[i] = rsqrtf(deg[i] + 1.0f);   // +1 = self loop; always > 0
}

// Single-block exclusive scan of cnt[NN] -> rowptr[NN+1]. 256 thr x 16 elems/chunk.
__global__ __launch_bounds__(256) void scan_kernel(const int* __restrict__ cnt,
        int* __restrict__ rowptr) {
    __shared__ int sdata[256];
    __shared__ int sbase;
    int t = threadIdx.x;
    if (t == 0) { sbase = 0; rowptr[0] = 0; }
    __syncthreads();
    for (int c0 = 0; c0 < NN; c0 += 4096) {
        int vals[16];
        int sum = 0;
        int base_idx = c0 + t * 16;
        #pragma unroll
        for (int k = 0; k < 16; ++k) {
            int idx = base_idx + k;
            vals[k] = (idx < NN) ? cnt[idx] : 0;
            sum += vals[k];
        }
        sdata[t] = sum;
        __syncthreads();
        for (int off = 1; off < 256; off <<= 1) {
            int v = (t >= off) ? sdata[t - off] : 0;
            __syncthreads();
            sdata[t] += v;
            __syncthreads();
        }
        int running = sbase + sdata[t] - sum;   // exclusive prefix for this thread
        #pragma unroll
        for (int k = 0; k < 16; ++k) {
            int idx = base_idx + k;
            running += vals[k];
            if (idx < NN) rowptr[idx + 1] = running;
        }
        __syncthreads();                        // all reads of sbase done
        if (t == 0) sbase += sdata[255];
        __syncthreads();
    }
}

// CSR scatter: slot = rowptr[d] + cursor[d]++ ; store src and coef.
__global__ __launch_bounds__(256) void scatter_kernel(const int* __restrict__ src,
        const int* __restrict__ dst, const float* __restrict__ ew,
        const float* __restrict__ dinv, const int* __restrict__ rowptr,
        int* __restrict__ cursor, int* __restrict__ esrc, float* __restrict__ ecoef) {
    int e = blockIdx.x * 256 + threadIdx.x;
    if (e >= NE) return;
    int s = src[e], d = dst[e];
    int pos = atomicAdd(&cursor[d], 1);
    int idx = rowptr[d] + pos;
    esrc[idx] = s;
    ecoef[idx] = dinv[s] * ew[e] * dinv[d];
}

// C[M,N] = A[M,K]*B[K,N], row-major. Requires N%64==0, K%16==0.
__global__ __launch_bounds__(256) void gemm_kernel(const float* __restrict__ A,
        const float* __restrict__ B, float* __restrict__ C, int M, int N, int K) {
    const int BM = 64, BN = 64, BK = 16;
    __shared__ float As[BK][BM + 1];
    __shared__ float Bs[BK][BN];
    int bm = blockIdx.y * BM, bn = blockIdx.x * BN;
    int tid = threadIdx.x;
    int tx = tid & 15, ty = tid >> 4;
    float acc[4][4] = {};
    for (int k0 = 0; k0 < K; k0 += BK) {
        int ar = tid >> 2, ak = (tid & 3) << 2;
        float4 av = make_float4(0.f, 0.f, 0.f, 0.f);
        if (bm + ar < M) av = *(const float4*)(A + (size_t)(bm + ar) * K + k0 + ak);
        As[ak + 0][ar] = av.x; As[ak + 1][ar] = av.y;
        As[ak + 2][ar] = av.z; As[ak + 3][ar] = av.w;
        int bk = tid >> 4, bc = (tid & 15) << 2;
        *(float4*)(&Bs[bk][bc]) = *(const float4*)(B + (size_t)(k0 + bk) * N + bn + bc);
        __syncthreads();
        #pragma unroll
        for (int k = 0; k < BK; ++k) {
            float a[4], b[4];
            #pragma unroll
            for (int i = 0; i < 4; ++i) a[i] = As[k][ty * 4 + i];
            #pragma unroll
            for (int j = 0; j < 4; ++j) b[j] = Bs[k][tx * 4 + j];
            #pragma unroll
            for (int i = 0; i < 4; ++i)
                #pragma unroll
                for (int j = 0; j < 4; ++j)
                    acc[i][j] += a[i] * b[j];
        }
        __syncthreads();
    }
    #pragma unroll
    for (int i = 0; i < 4; ++i) {
        int r = bm + ty * 4 + i;
        if (r < M) {
            float4 v = make_float4(acc[i][0], acc[i][1], acc[i][2], acc[i][3]);
            *(float4*)(C + (size_t)r * N + bn + tx * 4) = v;
        }
    }
}

// One wave per node: gather+accumulate in-edges, fused self-loop+bias(+relu).
template<int F, int RELU>
__global__ __launch_bounds__(256) void agg_csr_kernel(
        const int* __restrict__ rowptr, const int* __restrict__ esrc,
        const float* __restrict__ ecoef, const float* __restrict__ H,
        const float* __restrict__ dinv, const float* __restrict__ bias,
        float* __restrict__ out) {
    constexpr int VPT = F / 64;
    int node = blockIdx.x * 4 + (threadIdx.x >> 6);
    if (node >= NN) return;
    int lane = threadIdx.x & 63;
    float acc[VPT] = {};
    int beg = rowptr[node], end = rowptr[node + 1];
    int j = beg;
    for (; j + 2 <= end; j += 2) {
        int s0 = __builtin_amdgcn_readfirstlane(esrc[j]);
        int s1 = __builtin_amdgcn_readfirstlane(esrc[j + 1]);
        float c0 = __uint_as_float(__builtin_amdgcn_readfirstlane(__float_as_uint(ecoef[j])));
        float c1 = __uint_as_float(__builtin_amdgcn_readfirstlane(__float_as_uint(ecoef[j + 1])));
        const float* r0 = H + (size_t)s0 * F + lane * VPT;
        const float* r1 = H + (size_t)s1 * F + lane * VPT;
        float v0[VPT], v1[VPT];
        #pragma unroll
        for (int k = 0; k < VPT; ++k) v0[k] = r0[k];
        #pragma unroll
        for (int k = 0; k < VPT; ++k) v1[k] = r1[k];
        #pragma unroll
        for (int k = 0; k < VPT; ++k) acc[k] += v0[k] * c0;
        #pragma unroll
        for (int k = 0; k < VPT; ++k) acc[k] += v1[k] * c1;
    }
    if (j < end) {
        int s0 = __builtin_amdgcn_readfirstlane(esrc[j]);
        float c0 = __uint_as_float(__builtin_amdgcn_readfirstlane(__float_as_uint(ecoef[j])));
        const float* r0 = H + (size_t)s0 * F + lane * VPT;
        #pragma unroll
        for (int k = 0; k < VPT; ++k) acc[k] += r0[k] * c0;
    }
    // self-loop (coef = dinv^2) + bias (+ relu)
    float di = dinv[node];
    float sc = di * di;
    const float* hr = H + (size_t)node * F + lane * VPT;
    float* o = out + (size_t)node * F + lane * VPT;
    #pragma unroll
    for (int k = 0; k < VPT; ++k) {
        float v = acc[k] + hr[k] * sc + bias[lane * VPT + k];
        if (RELU) v = v > 0.0f ? v : 0.0f;
        o[k] = v;
    }
}

extern "C" void kernel_launch(void* const* d_in, const int* in_sizes, int n_in,
                              void* d_out, int out_size, void* d_ws, size_t ws_size,
                              hipStream_t stream) {
    const float* x  = (const float*)d_in[0];
    const int*   ei = (const int*)d_in[1];     // [2, NE] int32
    const float* ew = (const float*)d_in[2];
    const float* W1 = (const float*)d_in[3];
    const float* b1 = (const float*)d_in[4];
    const float* W2 = (const float*)d_in[5];
    const float* b2 = (const float*)d_in[6];
    const int* src = ei;
    const int* dst = ei + NE;
    float* out = (float*)d_out;

    // workspace layout (4-byte units):
    float* ws     = (float*)d_ws;
    float* deg    = ws;                         // NN floats (dinv after dinv_kernel)
    int*   rowptr = (int*)(ws + 50048);         // NN+1 ints
    int*   cnt    = (int*)(ws + 100096);        // NN ints (reused as cursor)
    int*   esrc   = (int*)(ws + 150144);        // NE ints
    float* ecoef  = ws + 150144 + NE;           // NE floats
    float* H1     = ws + 150144 + 2 * NE;       // NN*128 floats (H2 reuses)
    float* A1     = H1 + 6400000;               // NN*128 floats
    // total = 16,150,144 * 4B = 64.6 MB

    hipMemsetAsync(deg, 0, NN * sizeof(float), stream);
    hipMemsetAsync(cnt, 0, NN * sizeof(int), stream);

    deg_count_kernel<<<NE / 256, 256, 0, stream>>>(dst, ew, deg, cnt);
    dinv_kernel<<<(NN + 255) / 256, 256, 0, stream>>>(deg);
    scan_kernel<<<1, 256, 0, stream>>>(cnt, rowptr);
    hipMemsetAsync(cnt, 0, NN * sizeof(int), stream);   // cursor = 0
    scatter_kernel<<<NE / 256, 256, 0, stream>>>(src, dst, ew, deg, rowptr, cnt, esrc, ecoef);

    // Layer 1: H1 = x @ W1  [50000,256]x[256,128]
    gemm_kernel<<<dim3(2, (NN + 63) / 64), 256, 0, stream>>>(x, W1, H1, NN, 128, 256);
    agg_csr_kernel<128, 1><<<(NN + 3) / 4, 256, 0, stream>>>(rowptr, esrc, ecoef, H1, deg, b1, A1);

    // Layer 2: H2 = A1 @ W2  [50000,128]x[128,64]  (H2 in H1's buffer)
    gemm_kernel<<<dim3(1, (NN + 63) / 64), 256, 0, stream>>>(A1, W2, H1, NN, 64, 128);
    agg_csr_kernel<64, 0><<<(NN + 3) / 4, 256, 0, stream>>>(rowptr, esrc, ecoef, H1, deg, b2, out);
}

// Round 3
// 411.110 us; speedup vs baseline: 10.5030x; 1.5968x over previous
//
#include <hip/hip_runtime.h>

#define NN 50000
#define NE 1600000

typedef short bf16x8 __attribute__((ext_vector_type(8)));
typedef float f32x4 __attribute__((ext_vector_type(4)));

static __device__ __forceinline__ unsigned f2bf(float f) {
    union { float f; unsigned u; } v; v.f = f;
    return (v.u + 0x7FFF + ((v.u >> 16) & 1)) >> 16;   // RNE
}

// rank[e] = arrival order at dst[e]; cnt[d] = in-degree count
__global__ __launch_bounds__(256) void rank_kernel(const int* __restrict__ dst,
        int* __restrict__ cnt, int* __restrict__ rank) {
    int e = blockIdx.x * 256 + threadIdx.x;
    if (e < NE) rank[e] = atomicAdd(&cnt[dst[e]], 1);
}

// block-local inclusive scan of cnt -> rowptr[idx+1]; block totals -> bsum
__global__ __launch_bounds__(256) void scan1_kernel(const int* __restrict__ cnt,
        int* __restrict__ rowptr, int* __restrict__ bsum) {
    __shared__ int sd[256];
    int t = threadIdx.x;
    int idx = blockIdx.x * 256 + t;
    int v = (idx < NN) ? cnt[idx] : 0;
    sd[t] = v;
    __syncthreads();
    for (int off = 1; off < 256; off <<= 1) {
        int x = (t >= off) ? sd[t - off] : 0;
        __syncthreads();
        sd[t] += x;
        __syncthreads();
    }
    if (idx < NN) rowptr[idx + 1] = sd[t];
    if (t == 255) bsum[blockIdx.x] = sd[255];
}

// exclusive scan of bsum (196 entries) in place; rowptr[0]=0
__global__ __launch_bounds__(256) void scan2_kernel(int* __restrict__ bsum,
        int* __restrict__ rowptr) {
    __shared__ int sd[256];
    int t = threadIdx.x;
    int v = (t < 196) ? bsum[t] : 0;
    sd[t] = v;
    __syncthreads();
    for (int off = 1; off < 256; off <<= 1) {
        int x = (t >= off) ? sd[t - off] : 0;
        __syncthreads();
        sd[t] += x;
        __syncthreads();
    }
    if (t < 196) bsum[t] = sd[t] - v;
    if (t == 0) rowptr[0] = 0;
}

__global__ __launch_bounds__(256) void scan3_kernel(int* __restrict__ rowptr,
        const int* __restrict__ bsum) {
    int idx = blockIdx.x * 256 + threadIdx.x;
    if (idx < NN) rowptr[idx + 1] += bsum[blockIdx.x];
}

// atomic-free CSR scatter: edata[slot] = {src, bits(ew)}
__global__ __launch_bounds__(256) void scatter_kernel(const int* __restrict__ src,
        const int* __restrict__ dst, const float* __restrict__ ew,
        const int* __restrict__ rank, const int* __restrict__ rowptr,
        int2* __restrict__ edata) {
    int e = blockIdx.x * 256 + threadIdx.x;
    if (e >= NE) return;
    int idx = rowptr[dst[e]] + rank[e];
    edata[idx] = make_int2(src[e], __float_as_int(ew[e]));
}

// wave per node: dinv[n] = rsqrt(1 + sum of ew over in-edges)
__global__ __launch_bounds__(256) void degdinv_kernel(const int* __restrict__ rowptr,
        const int2* __restrict__ edata, float* __restrict__ dinv) {
    int node = blockIdx.x * 4 + (threadIdx.x >> 6);
    if (node >= NN) return;
    int lane = threadIdx.x & 63;
    int beg = rowptr[node], end = rowptr[node + 1];
    float s = 0.0f;
    for (int i = beg + lane; i < end; i += 64) s += __int_as_float(edata[i].y);
    #pragma unroll
    for (int off = 32; off > 0; off >>= 1) s += __shfl_down(s, off);
    if (lane == 0) dinv[node] = rsqrtf(s + 1.0f);
}

// edata[i].y = bits( dinv[src] * ew )   (dinv[dst] applied in agg epilogue)
__global__ __launch_bounds__(256) void coef_kernel(int2* __restrict__ edata,
        const float* __restrict__ dinv) {
    int i = blockIdx.x * 256 + threadIdx.x;
    if (i >= NE) return;
    int2 e = edata[i];
    edata[i].y = __float_as_int(dinv[e.x] * __int_as_float(e.y));
}

// Wt[n*K + k] = bf16(W[k*N + n]);  N = 1<<nshift
__global__ __launch_bounds__(256) void wt_kernel(const float* __restrict__ W,
        ushort* __restrict__ Wt, int K, int nshift) {
    int idx = blockIdx.x * 256 + threadIdx.x;
    if (idx >= (K << nshift)) return;
    int k = idx >> nshift, n = idx & ((1 << nshift) - 1);
    Wt[(size_t)n * K + k] = (ushort)f2bf(W[idx]);
}

// C[M,N] = A[M,K] x B[K,N], A fp32, B given as Wt[n][k] bf16. fp32 accumulate.
// Block 256 = 4 waves, tile 64x64, BK=64. Requires K%64==0, N%64==0.
__global__ __launch_bounds__(256) void gemm_bf16_kernel(const float* __restrict__ A,
        const ushort* __restrict__ Bt, float* __restrict__ C, int M, int N, int K) {
    __shared__ __align__(16) ushort As[64][72];   // pad 8: frag reads 2-way = free
    __shared__ __align__(16) ushort Bs[64][72];
    int tid = threadIdx.x;
    int bm = blockIdx.y * 64, bn = blockIdx.x * 64;
    int w = tid >> 6, lane = tid & 63;
    int m = lane & 15, quad = lane >> 4;
    f32x4 acc[4] = {};
    int r = tid >> 2, ks0 = (tid & 3) * 16;
    int grow = bm + r; if (grow >= M) grow = M - 1;      // clamp (stores guarded)
    const float* ap = A + (size_t)grow * K + ks0;
    const ushort* bp = Bt + (size_t)(bn + r) * K + ks0;
    for (int k0 = 0; k0 < K; k0 += 64) {
        float4 f0 = *(const float4*)(ap + k0);
        float4 f1 = *(const float4*)(ap + k0 + 4);
        float4 f2 = *(const float4*)(ap + k0 + 8);
        float4 f3 = *(const float4*)(ap + k0 + 12);
        uint4 bv0 = *(const uint4*)(bp + k0);
        uint4 bv1 = *(const uint4*)(bp + k0 + 8);
        uint4 pa, pb;
        pa.x = f2bf(f0.x) | (f2bf(f0.y) << 16);
        pa.y = f2bf(f0.z) | (f2bf(f0.w) << 16);
        pa.z = f2bf(f1.x) | (f2bf(f1.y) << 16);
        pa.w = f2bf(f1.z) | (f2bf(f1.w) << 16);
        pb.x = f2bf(f2.x) | (f2bf(f2.y) << 16);
        pb.y = f2bf(f2.z) | (f2bf(f2.w) << 16);
        pb.z = f2bf(f3.x) | (f2bf(f3.y) << 16);
        pb.w = f2bf(f3.z) | (f2bf(f3.w) << 16);
        __syncthreads();                       // prev compute done; loads overlapped
        *(uint4*)&As[r][ks0] = pa;
        *(uint4*)&As[r][ks0 + 8] = pb;
        *(uint4*)&Bs[r][ks0] = bv0;
        *(uint4*)&Bs[r][ks0 + 8] = bv1;
        __syncthreads();
        #pragma unroll
        for (int ks = 0; ks < 2; ++ks) {
            bf16x8 a = *(const bf16x8*)&As[w * 16 + m][ks * 32 + quad * 8];
            #pragma unroll
            for (int t = 0; t < 4; ++t) {
                bf16x8 b = *(const bf16x8*)&Bs[t * 16 + m][ks * 32 + quad * 8];
                acc[t] = __builtin_amdgcn_mfma_f32_16x16x32_bf16(a, b, acc[t], 0, 0, 0);
            }
        }
    }
    // C/D layout: col=lane&15, row=quad*4+reg  [m89/m91 verified]
    #pragma unroll
    for (int t = 0; t < 4; ++t) {
        int col = bn + t * 16 + m;
        #pragma unroll
        for (int rg = 0; rg < 4; ++rg) {
            int row = bm + w * 16 + quad * 4 + rg;
            if (row < M) C[(size_t)row * N + col] = acc[t][rg];
        }
    }
}

// wave per node: out[n] = dinv[n]*sum(c_j*H[s_j]) + dinv[n]^2*H[n] + bias (opt relu)
template<int F, int RELU>
__global__ __launch_bounds__(256) void agg_csr_kernel(
        const int* __restrict__ rowptr, const int2* __restrict__ edata,
        const float* __restrict__ H, const float* __restrict__ dinv,
        const float* __restrict__ bias, float* __restrict__ out) {
    constexpr int VPT = F / 64;
    int node = blockIdx.x * 4 + (threadIdx.x >> 6);
    if (node >= NN) return;
    int lane = threadIdx.x & 63;
    int beg = rowptr[node], end = rowptr[node + 1];
    float acc[VPT] = {};
    const float* Hl = H + lane * VPT;
    for (int chunk = beg; chunk < end; chunk += 64) {
        int nch = end - chunk; if (nch > 64) nch = 64;
        int2 ed = make_int2(0, 0);
        if (lane < nch) ed = edata[chunk + lane];        // coalesced metadata load
        int j = 0;
        for (; j + 4 <= nch; j += 4) {
            int s0 = __shfl(ed.x, j + 0); float c0 = __int_as_float(__shfl(ed.y, j + 0));
            int s1 = __shfl(ed.x, j + 1); float c1 = __int_as_float(__shfl(ed.y, j + 1));
            int s2 = __shfl(ed.x, j + 2); float c2 = __int_as_float(__shfl(ed.y, j + 2));
            int s3 = __shfl(ed.x, j + 3); float c3 = __int_as_float(__shfl(ed.y, j + 3));
            const float* r0 = Hl + (size_t)s0 * F;
            const float* r1 = Hl + (size_t)s1 * F;
            const float* r2 = Hl + (size_t)s2 * F;
            const float* r3 = Hl + (size_t)s3 * F;
            #pragma unroll
            for (int k = 0; k < VPT; ++k) acc[k] += r0[k] * c0;
            #pragma unroll
            for (int k = 0; k < VPT; ++k) acc[k] += r1[k] * c1;
            #pragma unroll
            for (int k = 0; k < VPT; ++k) acc[k] += r2[k] * c2;
            #pragma unroll
            for (int k = 0; k < VPT; ++k) acc[k] += r3[k] * c3;
        }
        for (; j < nch; ++j) {
            int s0 = __shfl(ed.x, j); float c0 = __int_as_float(__shfl(ed.y, j));
            const float* r0 = Hl + (size_t)s0 * F;
            #pragma unroll
            for (int k = 0; k < VPT; ++k) acc[k] += r0[k] * c0;
        }
    }
    float di = dinv[node];
    float sc = di * di;
    const float* hn = H + (size_t)node * F + lane * VPT;
    float* o = out + (size_t)node * F + lane * VPT;
    #pragma unroll
    for (int k = 0; k < VPT; ++k) {
        float v = di * acc[k] + sc * hn[k] + bias[lane * VPT + k];
        if (RELU) v = fmaxf(v, 0.0f);
        o[k] = v;
    }
}

extern "C" void kernel_launch(void* const* d_in, const int* in_sizes, int n_in,
                              void* d_out, int out_size, void* d_ws, size_t ws_size,
                              hipStream_t stream) {
    const float* x  = (const float*)d_in[0];
    const int*   ei = (const int*)d_in[1];
    const float* ew = (const float*)d_in[2];
    const float* W1 = (const float*)d_in[3];
    const float* b1 = (const float*)d_in[4];
    const float* W2 = (const float*)d_in[5];
    const float* b2 = (const float*)d_in[6];
    const int* src = ei;
    const int* dst = ei + NE;
    float* out = (float*)d_out;

    // workspace (dword offsets), total 16,150,528 dwords = 64.6 MB:
    float* ws     = (float*)d_ws;
    int*   cnt    = (int*)ws;                  // [0, 50048)  dead after scan1
    ushort* Wt1   = (ushort*)ws;               // aliases cnt (used after scan1)
    ushort* Wt2   = Wt1 + 32768;               // still inside cnt's 50048 dwords
    float* dinv   = ws + 50048;                // 50048
    int*   rowptr = (int*)(ws + 100096);       // 50064
    int*   bsum   = (int*)(ws + 150160);       // 256
    int2*  edata  = (int2*)(ws + 150528);      // 2*NE dwords
    float* H1     = ws + 3350528;              // NN*128 (H2 reuses)
    float* A1     = ws + 9750528;              // NN*128
    int*   rank   = (int*)A1;                  // aliases A1 (dead before agg1)

    hipMemsetAsync(cnt, 0, NN * sizeof(int), stream);
    rank_kernel<<<NE / 256, 256, 0, stream>>>(dst, cnt, rank);
    scan1_kernel<<<196, 256, 0, stream>>>(cnt, rowptr, bsum);
    scan2_kernel<<<1, 256, 0, stream>>>(bsum, rowptr);
    scan3_kernel<<<196, 256, 0, stream>>>(rowptr, bsum);
    wt_kernel<<<128, 256, 0, stream>>>(W1, Wt1, 256, 7);   // after scan1: cnt dead
    wt_kernel<<<32, 256, 0, stream>>>(W2, Wt2, 128, 6);
    scatter_kernel<<<NE / 256, 256, 0, stream>>>(src, dst, ew, rank, rowptr, edata);
    degdinv_kernel<<<12500, 256, 0, stream>>>(rowptr, edata, dinv);
    coef_kernel<<<NE / 256, 256, 0, stream>>>(edata, dinv);

    // Layer 1: H1 = x @ W1  -> agg -> A1 (relu)
    gemm_bf16_kernel<<<dim3(2, 782), 256, 0, stream>>>(x, Wt1, H1, NN, 128, 256);
    agg_csr_kernel<128, 1><<<12500, 256, 0, stream>>>(rowptr, edata, H1, dinv, b1, A1);

    // Layer 2: H2 = A1 @ W2 (into H1 buffer) -> agg -> out
    gemm_bf16_kernel<<<dim3(1, 782), 256, 0, stream>>>(A1, Wt2, H1, NN, 64, 128);
    agg_csr_kernel<64, 0><<<12500, 256, 0, stream>>>(rowptr, edata, H1, dinv, b2, out);
}

// Round 4
// 329.849 us; speedup vs baseline: 13.0906x; 1.2464x over previous
//
#include <hip/hip_runtime.h>

#define NN 50000
#define NE 1600000

typedef short bf16x8 __attribute__((ext_vector_type(8)));
typedef float f32x4 __attribute__((ext_vector_type(4)));

static __device__ __forceinline__ unsigned f2bf(float f) {
    union { float f; unsigned u; } v; v.f = f;
    return (v.u + 0x7FFF + ((v.u >> 16) & 1)) >> 16;   // RNE
}

// rank[e] = arrival order at dst[e]; cnt[d] = in-degree count
__global__ __launch_bounds__(256) void rank_kernel(const int* __restrict__ dst,
        int* __restrict__ cnt, int* __restrict__ rank) {
    int e = blockIdx.x * 256 + threadIdx.x;
    if (e < NE) rank[e] = atomicAdd(&cnt[dst[e]], 1);
}

// block-local inclusive scan of cnt -> rowptr[idx+1]; block totals -> bsum
__global__ __launch_bounds__(256) void scan1_kernel(const int* __restrict__ cnt,
        int* __restrict__ rowptr, int* __restrict__ bsum) {
    __shared__ int sd[256];
    int t = threadIdx.x;
    int idx = blockIdx.x * 256 + t;
    int v = (idx < NN) ? cnt[idx] : 0;
    sd[t] = v;
    __syncthreads();
    for (int off = 1; off < 256; off <<= 1) {
        int x = (t >= off) ? sd[t - off] : 0;
        __syncthreads();
        sd[t] += x;
        __syncthreads();
    }
    if (idx < NN) rowptr[idx + 1] = sd[t];
    if (t == 255) bsum[blockIdx.x] = sd[255];
}

// exclusive scan of bsum (196 entries) in place; rowptr[0]=0
__global__ __launch_bounds__(256) void scan2_kernel(int* __restrict__ bsum,
        int* __restrict__ rowptr) {
    __shared__ int sd[256];
    int t = threadIdx.x;
    int v = (t < 196) ? bsum[t] : 0;
    sd[t] = v;
    __syncthreads();
    for (int off = 1; off < 256; off <<= 1) {
        int x = (t >= off) ? sd[t - off] : 0;
        __syncthreads();
        sd[t] += x;
        __syncthreads();
    }
    if (t < 196) bsum[t] = sd[t] - v;
    if (t == 0) rowptr[0] = 0;
}

__global__ __launch_bounds__(256) void scan3_kernel(int* __restrict__ rowptr,
        const int* __restrict__ bsum) {
    int idx = blockIdx.x * 256 + threadIdx.x;
    if (idx < NN) rowptr[idx + 1] += bsum[blockIdx.x];
}

// atomic-free CSR scatter: edata[slot] = {src, bits(ew)}
__global__ __launch_bounds__(256) void scatter_kernel(const int* __restrict__ src,
        const int* __restrict__ dst, const float* __restrict__ ew,
        const int* __restrict__ rank, const int* __restrict__ rowptr,
        int2* __restrict__ edata) {
    int e = blockIdx.x * 256 + threadIdx.x;
    if (e >= NE) return;
    int idx = rowptr[dst[e]] + rank[e];
    edata[idx] = make_int2(src[e], __float_as_int(ew[e]));
}

// wave per node: dinv[n] = rsqrt(1 + sum of ew over in-edges)
__global__ __launch_bounds__(256) void degdinv_kernel(const int* __restrict__ rowptr,
        const int2* __restrict__ edata, float* __restrict__ dinv) {
    int node = blockIdx.x * 4 + (threadIdx.x >> 6);
    if (node >= NN) return;
    int lane = threadIdx.x & 63;
    int beg = rowptr[node], end = rowptr[node + 1];
    float s = 0.0f;
    for (int i = beg + lane; i < end; i += 64) s += __int_as_float(edata[i].y);
    #pragma unroll
    for (int off = 32; off > 0; off >>= 1) s += __shfl_down(s, off);
    if (lane == 0) dinv[node] = rsqrtf(s + 1.0f);
}

// edata[i].y = bits( dinv[src] * ew )   (dinv[dst] applied in agg epilogue)
__global__ __launch_bounds__(256) void coef_kernel(int2* __restrict__ edata,
        const float* __restrict__ dinv) {
    int i = blockIdx.x * 256 + threadIdx.x;
    if (i >= NE) return;
    int2 e = edata[i];
    edata[i].y = __float_as_int(dinv[e.x] * __int_as_float(e.y));
}

// Wt[n*K + k] = bf16(W[k*N + n]);  N = 1<<nshift
__global__ __launch_bounds__(256) void wt_kernel(const float* __restrict__ W,
        ushort* __restrict__ Wt, int K, int nshift) {
    int idx = blockIdx.x * 256 + threadIdx.x;
    if (idx >= (K << nshift)) return;
    int k = idx >> nshift, n = idx & ((1 << nshift) - 1);
    Wt[(size_t)n * K + k] = (ushort)f2bf(W[idx]);
}

// C[M,N](bf16) = A[M,K](fp32) x Bt[n][k](bf16). fp32 acc. K%64==0, N%64==0.
__global__ __launch_bounds__(256) void gemm_a32_kernel(const float* __restrict__ A,
        const ushort* __restrict__ Bt, ushort* __restrict__ C, int M, int N, int K) {
    __shared__ __align__(16) ushort As[64][72];
    __shared__ __align__(16) ushort Bs[64][72];
    int tid = threadIdx.x;
    int bm = blockIdx.y * 64, bn = blockIdx.x * 64;
    int w = tid >> 6, lane = tid & 63;
    int m = lane & 15, quad = lane >> 4;
    f32x4 acc[4] = {};
    int r = tid >> 2, ks0 = (tid & 3) * 16;
    int grow = bm + r; if (grow >= M) grow = M - 1;
    const float* ap = A + (size_t)grow * K + ks0;
    const ushort* bp = Bt + (size_t)(bn + r) * K + ks0;
    for (int k0 = 0; k0 < K; k0 += 64) {
        float4 f0 = *(const float4*)(ap + k0);
        float4 f1 = *(const float4*)(ap + k0 + 4);
        float4 f2 = *(const float4*)(ap + k0 + 8);
        float4 f3 = *(const float4*)(ap + k0 + 12);
        uint4 bv0 = *(const uint4*)(bp + k0);
        uint4 bv1 = *(const uint4*)(bp + k0 + 8);
        uint4 pa, pb;
        pa.x = f2bf(f0.x) | (f2bf(f0.y) << 16);
        pa.y = f2bf(f0.z) | (f2bf(f0.w) << 16);
        pa.z = f2bf(f1.x) | (f2bf(f1.y) << 16);
        pa.w = f2bf(f1.z) | (f2bf(f1.w) << 16);
        pb.x = f2bf(f2.x) | (f2bf(f2.y) << 16);
        pb.y = f2bf(f2.z) | (f2bf(f2.w) << 16);
        pb.z = f2bf(f3.x) | (f2bf(f3.y) << 16);
        pb.w = f2bf(f3.z) | (f2bf(f3.w) << 16);
        __syncthreads();
        *(uint4*)&As[r][ks0] = pa;
        *(uint4*)&As[r][ks0 + 8] = pb;
        *(uint4*)&Bs[r][ks0] = bv0;
        *(uint4*)&Bs[r][ks0 + 8] = bv1;
        __syncthreads();
        #pragma unroll
        for (int ks = 0; ks < 2; ++ks) {
            bf16x8 a = *(const bf16x8*)&As[w * 16 + m][ks * 32 + quad * 8];
            #pragma unroll
            for (int t = 0; t < 4; ++t) {
                bf16x8 b = *(const bf16x8*)&Bs[t * 16 + m][ks * 32 + quad * 8];
                acc[t] = __builtin_amdgcn_mfma_f32_16x16x32_bf16(a, b, acc[t], 0, 0, 0);
            }
        }
    }
    #pragma unroll
    for (int t = 0; t < 4; ++t) {
        int col = bn + t * 16 + m;
        #pragma unroll
        for (int rg = 0; rg < 4; ++rg) {
            int row = bm + w * 16 + quad * 4 + rg;
            if (row < M) C[(size_t)row * N + col] = (ushort)f2bf(acc[t][rg]);
        }
    }
}

// C[M,N](bf16) = A[M,K](bf16) x Bt[n][k](bf16). fp32 acc. K%64==0, N%64==0.
__global__ __launch_bounds__(256) void gemm_a16_kernel(const ushort* __restrict__ A,
        const ushort* __restrict__ Bt, ushort* __restrict__ C, int M, int N, int K) {
    __shared__ __align__(16) ushort As[64][72];
    __shared__ __align__(16) ushort Bs[64][72];
    int tid = threadIdx.x;
    int bm = blockIdx.y * 64, bn = blockIdx.x * 64;
    int w = tid >> 6, lane = tid & 63;
    int m = lane & 15, quad = lane >> 4;
    f32x4 acc[4] = {};
    int r = tid >> 2, ks0 = (tid & 3) * 16;
    int grow = bm + r; if (grow >= M) grow = M - 1;
    const ushort* ap = A + (size_t)grow * K + ks0;
    const ushort* bp = Bt + (size_t)(bn + r) * K + ks0;
    for (int k0 = 0; k0 < K; k0 += 64) {
        uint4 av0 = *(const uint4*)(ap + k0);
        uint4 av1 = *(const uint4*)(ap + k0 + 8);
        uint4 bv0 = *(const uint4*)(bp + k0);
        uint4 bv1 = *(const uint4*)(bp + k0 + 8);
        __syncthreads();
        *(uint4*)&As[r][ks0] = av0;
        *(uint4*)&As[r][ks0 + 8] = av1;
        *(uint4*)&Bs[r][ks0] = bv0;
        *(uint4*)&Bs[r][ks0 + 8] = bv1;
        __syncthreads();
        #pragma unroll
        for (int ks = 0; ks < 2; ++ks) {
            bf16x8 a = *(const bf16x8*)&As[w * 16 + m][ks * 32 + quad * 8];
            #pragma unroll
            for (int t = 0; t < 4; ++t) {
                bf16x8 b = *(const bf16x8*)&Bs[t * 16 + m][ks * 32 + quad * 8];
                acc[t] = __builtin_amdgcn_mfma_f32_16x16x32_bf16(a, b, acc[t], 0, 0, 0);
            }
        }
    }
    #pragma unroll
    for (int t = 0; t < 4; ++t) {
        int col = bn + t * 16 + m;
        #pragma unroll
        for (int rg = 0; rg < 4; ++rg) {
            int row = bm + w * 16 + quad * 4 + rg;
            if (row < M) C[(size_t)row * N + col] = (ushort)f2bf(acc[t][rg]);
        }
    }
}

// LPN lanes per node (F = LPN*8 bf16 features, 16 B per lane).
// out[n] = dinv[n]*sum_j(c_j*H[s_j]) + dinv[n]^2*H[n] + bias  (opt relu)
template<int F, int LPN, int RELU, int OUTBF>
__global__ __launch_bounds__(256) void agg_csr_kernel(
        const int* __restrict__ rowptr, const int2* __restrict__ edata,
        const ushort* __restrict__ H, const float* __restrict__ dinv,
        const float* __restrict__ bias, void* __restrict__ outv) {
    constexpr int NPB = 256 / LPN;
    int node = blockIdx.x * NPB + threadIdx.x / LPN;
    if (node >= NN) return;
    int glane = threadIdx.x & (LPN - 1);
    int gb = (threadIdx.x & 63) & ~(LPN - 1);     // group base lane within wave
    int beg = rowptr[node], end = rowptr[node + 1];
    float acc[8] = {};
    const ushort* Hl = H + (size_t)glane * 8;
    for (int chunk = beg; chunk < end; chunk += LPN) {
        int nch = end - chunk; if (nch > LPN) nch = LPN;
        int2 ed = make_int2(0, 0);
        if (glane < nch) ed = edata[chunk + glane];
        int j = 0;
        for (; j + 2 <= nch; j += 2) {
            int s0 = __shfl(ed.x, gb + j);
            float c0 = __int_as_float(__shfl(ed.y, gb + j));
            int s1 = __shfl(ed.x, gb + j + 1);
            float c1 = __int_as_float(__shfl(ed.y, gb + j + 1));
            uint4 h0 = *(const uint4*)(Hl + (size_t)s0 * F);
            uint4 h1 = *(const uint4*)(Hl + (size_t)s1 * F);
            const unsigned* u0 = (const unsigned*)&h0;
            const unsigned* u1 = (const unsigned*)&h1;
            #pragma unroll
            for (int q = 0; q < 4; ++q) {
                acc[2*q]   += __uint_as_float(u0[q] << 16) * c0;
                acc[2*q+1] += __uint_as_float(u0[q] & 0xFFFF0000u) * c0;
            }
            #pragma unroll
            for (int q = 0; q < 4; ++q) {
                acc[2*q]   += __uint_as_float(u1[q] << 16) * c1;
                acc[2*q+1] += __uint_as_float(u1[q] & 0xFFFF0000u) * c1;
            }
        }
        if (j < nch) {
            int s0 = __shfl(ed.x, gb + j);
            float c0 = __int_as_float(__shfl(ed.y, gb + j));
            uint4 h0 = *(const uint4*)(Hl + (size_t)s0 * F);
            const unsigned* u0 = (const unsigned*)&h0;
            #pragma unroll
            for (int q = 0; q < 4; ++q) {
                acc[2*q]   += __uint_as_float(u0[q] << 16) * c0;
                acc[2*q+1] += __uint_as_float(u0[q] & 0xFFFF0000u) * c0;
            }
        }
    }
    float di = dinv[node];
    float sc = di * di;
    uint4 hn = *(const uint4*)(Hl + (size_t)node * F);
    const unsigned* un = (const unsigned*)&hn;
    float4 bv0 = *(const float4*)(bias + glane * 8);
    float4 bv1 = *(const float4*)(bias + glane * 8 + 4);
    float v[8];
    const float* bb = (const float*)&bv0;
    #pragma unroll
    for (int q = 0; q < 4; ++q) {
        v[2*q]   = di * acc[2*q]   + sc * __uint_as_float(un[q] << 16);
        v[2*q+1] = di * acc[2*q+1] + sc * __uint_as_float(un[q] & 0xFFFF0000u);
    }
    v[0] += bv0.x; v[1] += bv0.y; v[2] += bv0.z; v[3] += bv0.w;
    v[4] += bv1.x; v[5] += bv1.y; v[6] += bv1.z; v[7] += bv1.w;
    (void)bb;
    if (RELU) {
        #pragma unroll
        for (int k = 0; k < 8; ++k) v[k] = fmaxf(v[k], 0.0f);
    }
    if (OUTBF) {
        uint4 o;
        o.x = f2bf(v[0]) | (f2bf(v[1]) << 16);
        o.y = f2bf(v[2]) | (f2bf(v[3]) << 16);
        o.z = f2bf(v[4]) | (f2bf(v[5]) << 16);
        o.w = f2bf(v[6]) | (f2bf(v[7]) << 16);
        *(uint4*)((ushort*)outv + (size_t)node * F + glane * 8) = o;
    } else {
        float* o = (float*)outv + (size_t)node * F + glane * 8;
        *(float4*)(o)     = make_float4(v[0], v[1], v[2], v[3]);
        *(float4*)(o + 4) = make_float4(v[4], v[5], v[6], v[7]);
    }
}

extern "C" void kernel_launch(void* const* d_in, const int* in_sizes, int n_in,
                              void* d_out, int out_size, void* d_ws, size_t ws_size,
                              hipStream_t stream) {
    const float* x  = (const float*)d_in[0];
    const int*   ei = (const int*)d_in[1];
    const float* ew = (const float*)d_in[2];
    const float* W1 = (const float*)d_in[3];
    const float* b1 = (const float*)d_in[4];
    const float* W2 = (const float*)d_in[5];
    const float* b2 = (const float*)d_in[6];
    const int* src = ei;
    const int* dst = ei + NE;
    float* out = (float*)d_out;

    // workspace (dword offsets):
    float* ws     = (float*)d_ws;
    int*   cnt    = (int*)ws;                  // [0, 50048)  dead after scan1
    ushort* Wt1   = (ushort*)ws;               // aliases cnt (W1^T bf16: 16384 dw)
    ushort* Wt2   = Wt1 + 32768;               // +4096 dw, still < 50048
    float* dinv   = ws + 50048;                // 50048 dw
    int*   rowptr = (int*)(ws + 100096);       // 50064 dw
    int*   bsum   = (int*)(ws + 150160);       // 368 dw (padded)
    int2*  edata  = (int2*)(ws + 150528);      // 3.2M dw
    ushort* H1    = (ushort*)(ws + 3350528);   // 50000*128 bf16 = 3.2M dw (H2 reuses)
    ushort* A1    = (ushort*)(ws + 6550528);   // 50000*128 bf16 = 3.2M dw
    int*   rank   = (int*)A1;                  // aliases A1 (dead before agg1 writes)
    // total 9,750,528 dw = 39.0 MB

    hipMemsetAsync(cnt, 0, NN * sizeof(int), stream);
    rank_kernel<<<NE / 256, 256, 0, stream>>>(dst, cnt, rank);
    scan1_kernel<<<196, 256, 0, stream>>>(cnt, rowptr, bsum);
    scan2_kernel<<<1, 256, 0, stream>>>(bsum, rowptr);
    scan3_kernel<<<196, 256, 0, stream>>>(rowptr, bsum);
    wt_kernel<<<128, 256, 0, stream>>>(W1, Wt1, 256, 7);   // cnt dead after scan1
    wt_kernel<<<32, 256, 0, stream>>>(W2, Wt2, 128, 6);
    scatter_kernel<<<NE / 256, 256, 0, stream>>>(src, dst, ew, rank, rowptr, edata);
    degdinv_kernel<<<12500, 256, 0, stream>>>(rowptr, edata, dinv);
    coef_kernel<<<NE / 256, 256, 0, stream>>>(edata, dinv);

    // Layer 1: H1(bf16) = x @ W1 -> agg -> A1(bf16, relu)
    gemm_a32_kernel<<<dim3(2, 782), 256, 0, stream>>>(x, Wt1, H1, NN, 128, 256);
    agg_csr_kernel<128, 16, 1, 1><<<3125, 256, 0, stream>>>(rowptr, edata, H1, dinv, b1, A1);

    // Layer 2: H2(bf16) = A1 @ W2 (into H1 buffer) -> agg -> out(fp32)
    gemm_a16_kernel<<<dim3(1, 782), 256, 0, stream>>>(A1, Wt2, H1, NN, 64, 128);
    agg_csr_kernel<64, 8, 0, 0><<<1563, 256, 0, stream>>>(rowptr, edata, H1, dinv, b2, out);
}